// Round 6
// baseline (580.499 us; speedup 1.0000x reference)
//
#include <hip/hip_runtime.h>
#include <stdint.h>

typedef int  v4i  __attribute__((ext_vector_type(4)));
typedef int  v16i __attribute__((ext_vector_type(16)));
typedef unsigned int uint32;

#define BATCH 16384
#define FEAT  1024
#define GRID  512

// ---- workspace layout (bytes) ----
// Activations in MFMA B-fragment layout: frag16B index = (nb*32 + kk)*64 + lane
//   value(byte j) = act[row = kk*32 + (j&3) + 8*(j>>2) + 4*(lane>>5)][col = nb*32 + (lane&31)]
// Weights in matching A-fragment layout (same sigma permutation of K).
// W rows with BN scale < 0 are sign-folded (negated) at prep; threshold is a
// single int T2 per row, uniform test h >= T2.
#define OFF_ACTA 0u            // 16 MB  (Xp / H2)
#define OFF_ACTB 16777216u     // 16 MB  (H1 / H3)
#define OFF_WA1  33554432u     // 1 MB
#define OFF_WA2  34603008u     // 1 MB
#define OFF_WA3  35651584u     // 1 MB
#define OFF_WA4  36700160u     // 32 KB (10 rows + 22 zero-pad rows)
#define OFF_TH   36732928u     // 3*1024 int
#define OFF_BAR  36745216u     // barrier counters (64 B, memset to 0 pre-launch)

struct KArgs {
    const float *x, *W1, *W2, *W3, *W4;
    const float *g1, *b1, *m1, *v1;
    const float *g2, *b2, *m2, *v2;
    const float *g3, *b3, *m3, *v3;
    const float *tw, *tb, *tm, *tv;
    char *actA, *actB, *wa1, *wa2, *wa3, *wa4;
    int *TH;
    int *bar;
    float *out;
};

// ---------------------------------------------------------------------------
// Manual grid barrier (R6): plain launch + device-scope atomics. All 512
// blocks are co-resident by construction (2 blocks/CU x 256 CU). Agent-scope
// atomics + __threadfence give the cross-XCD L2 writeback/invalidate that
// layer N stores -> layer N+1 loads require. Bounded spin: deadlock becomes a
// loud wrong-answer, not a hang.
__device__ __forceinline__ void grid_barrier(int* bar)
{
    __syncthreads();
    if (threadIdx.x == 0) {
        __threadfence();                       // release my stores device-wide
        int g = __hip_atomic_load(&bar[1], __ATOMIC_RELAXED, __HIP_MEMORY_SCOPE_AGENT);
        int n = __hip_atomic_fetch_add(&bar[0], 1, __ATOMIC_ACQ_REL, __HIP_MEMORY_SCOPE_AGENT);
        if (n == GRID - 1) {
            __hip_atomic_store(&bar[0], 0,     __ATOMIC_RELAXED, __HIP_MEMORY_SCOPE_AGENT);
            __hip_atomic_store(&bar[1], g + 1, __ATOMIC_RELEASE, __HIP_MEMORY_SCOPE_AGENT);
        } else {
            long spin = 0;
            while (__hip_atomic_load(&bar[1], __ATOMIC_ACQUIRE, __HIP_MEMORY_SCOPE_AGENT) == g) {
                __builtin_amdgcn_s_sleep(8);
                if (++spin > (1L << 20)) break;   // ~0.2s bail-out
            }
        }
        __threadfence();                       // acquire: no stale lines ahead
    }
    __syncthreads();
}

// ---------------------------------------------------------------------------
__device__ __forceinline__ void gload16(const v4i* gsrc, v4i* ldst) {
    __builtin_amdgcn_global_load_lds(
        (const __attribute__((address_space(1))) void*)gsrc,
        (__attribute__((address_space(3))) void*)ldst, 16, 0, 0);
}

// ---------------------------------------------------------------------------
// One prep unit (verified R4 body): b<512: X pack | 512..607: W1..3 (sign-fold)
// | 608: W4 | 609: thresholds. T aliases the gemm LDS buffer.
__device__ __forceinline__ void prep_unit(int b, const KArgs& P,
                                          unsigned char (*T)[1040])
{
    if (b == 609) {                       // thresholds, sign-folded to single int
        for (int gid = threadIdx.x; gid < 3072; gid += 256) {
            int l = gid >> 10, j = gid & 1023;
            const float *g, *bb, *m, *v;
            if (l == 0)      { g = P.g1; bb = P.b1; m = P.m1; v = P.v1; }
            else if (l == 1) { g = P.g2; bb = P.b2; m = P.m2; v = P.v2; }
            else             { g = P.g3; bb = P.b3; m = P.m3; v = P.v3; }
            double gd = (double)g[j], bd = (double)bb[j], md = (double)m[j], vd = (double)v[j];
            double s = gd / sqrt(vd + 1e-5);
            int t2;
            if (s > 0.0)      t2 = (int)ceil(md - bd / s);           // bit = h >= t2
            else if (s < 0.0) t2 = -(int)floor(md - bd / s);         // folded
            else              t2 = (bd >= 0.0) ? -2000000 : 2000000; // always / never
            P.TH[gid] = t2;
        }
        return;
    }

    const float* src; char* dst; float thr; int nrows; int dblk;
    const float* gp = nullptr;
    if (b < 512)      { src = P.x  + (size_t)b * 32768;            dst = P.actA; dblk = b;      thr = 0.5f; nrows = 32; }
    else if (b < 544) { int mb = b - 512; src = P.W1 + (size_t)mb * 32768; dst = P.wa1; dblk = mb; thr = 0.0f; nrows = 32; gp = P.g1; }
    else if (b < 576) { int mb = b - 544; src = P.W2 + (size_t)mb * 32768; dst = P.wa2; dblk = mb; thr = 0.0f; nrows = 32; gp = P.g2; }
    else if (b < 608) { int mb = b - 576; src = P.W3 + (size_t)mb * 32768; dst = P.wa3; dblk = mb; thr = 0.0f; nrows = 32; gp = P.g3; }
    else              { src = P.W4; dst = P.wa4; dblk = 0; thr = 0.0f; nrows = 10; }

#pragma unroll
    for (int u = 0; u < 8; ++u) {
        int unit = threadIdx.x + u * 256;      // 0..2047
        int row  = unit >> 6;                  // 0..31
        int c16  = (unit & 63) << 4;           // col base (16 floats)
        uint32 wb0 = 0, wb1 = 0, wb2 = 0, wb3 = 0;
        if (row < nrows) {
            bool flipb = gp && (gp[dblk * 32 + row] < 0.0f);
            const float* p = src + (size_t)row * 1024 + c16;
            float4 f0 = *(const float4*)(p + 0);
            float4 f1 = *(const float4*)(p + 4);
            float4 f2 = *(const float4*)(p + 8);
            float4 f3 = *(const float4*)(p + 12);
#define BY(f) ((((f) >= thr) != flipb) ? 0x01u : 0xFFu)
            wb0 = BY(f0.x) | (BY(f0.y)<<8) | (BY(f0.z)<<16) | (BY(f0.w)<<24);
            wb1 = BY(f1.x) | (BY(f1.y)<<8) | (BY(f1.z)<<16) | (BY(f1.w)<<24);
            wb2 = BY(f2.x) | (BY(f2.y)<<8) | (BY(f2.z)<<16) | (BY(f2.w)<<24);
            wb3 = BY(f3.x) | (BY(f3.y)<<8) | (BY(f3.z)<<16) | (BY(f3.w)<<24);
#undef BY
        }
        *(uint4*)&T[row][c16] = make_uint4(wb0, wb1, wb2, wb3);
    }
    __syncthreads();

    int lane = threadIdx.x & 63;
    int wv   = threadIdx.x >> 6;
    int row  = lane & 31;
    int hb   = (lane >> 5) * 4;                 // +4h byte offset of sigma
#pragma unroll
    for (int u = 0; u < 8; ++u) {
        int kk = wv * 8 + u;
        const unsigned char* tr = &T[row][kk * 32 + hb];
        uint32 w0 = *(const uint32*)(tr + 0);
        uint32 w1 = *(const uint32*)(tr + 8);
        uint32 w2 = *(const uint32*)(tr + 16);
        uint32 w3 = *(const uint32*)(tr + 24);
        *(uint4*)(dst + (((size_t)dblk * 32 + kk) * 64 + lane) * 16) = make_uint4(w0, w1, w2, w3);
    }
    __syncthreads();     // T reusable by the next unit
}

// ---------------------------------------------------------------------------
// One binary GEMM layer (verified R4 body): H^T = sign( W_folded @ H^T - T2 ).
// 8-phase schedule: per phase batch-issue 4 ds_read_b128 for p+1, 2 staging
// gload_lds (phases 0..3), setprio(1) + 4 MFMAs + setprio(0). Counted
// vmcnt(1) + raw barrier per tile.
__device__ __forceinline__ void layer_gemm(const v4i* __restrict__ Af,
    const v4i* __restrict__ Bin, const int* __restrict__ th,
    v4i* __restrict__ Bout, v4i (*Bs)[2048], int* Tsh)
{
    const int tid  = threadIdx.x;
    const int lane = tid & 63;
    const int wv   = tid >> 6;
    int bid = blockIdx.x;
    int xcd = bid & 7;
    int i   = bid >> 3;
    int s   = xcd + ((i >> 3) << 3);           // n-split 0..63, XCD-grouped
    int m   = i & 7;                           // m-block (128 rows)
    int mt  = m * 4 + wv;                      // 32-row W tile 0..31
    int nb0 = s * 8;

    // stage tile 0 (8 gload_lds per wave)
#pragma unroll
    for (int j = 0; j < 8; ++j)
        gload16(Bin + (size_t)nb0 * 2048 + j * 256 + wv * 64 + lane,
                &Bs[0][j * 256 + wv * 64]);
    if (tid < 128) Tsh[tid] = th[m * 128 + tid];

    // A-fragments, full K (32 x 16B = 128 VGPR)
    v4i a[32];
    {
        const v4i* Ap = Af + (size_t)mt * 2048;
#pragma unroll
        for (int kk = 0; kk < 32; ++kk) a[kk] = Ap[kk * 64 + lane];
    }
    asm volatile("s_waitcnt vmcnt(0) lgkmcnt(0)" ::: "memory");
    __builtin_amdgcn_s_barrier();

    // hoist thresholds (negated) into 16 regs, C-layout order
    const int hi4 = (lane >> 5) * 4;
    int tq[16];
#pragma unroll
    for (int q = 0; q < 16; ++q) tq[q] = -Tsh[wv * 32 + (q & 3) + 8 * (q >> 2) + hi4];

    int buf = 0;
#pragma unroll 1
    for (int it = 0; it < 8; ++it) {
        const v4i* Bb = &Bs[buf][0];
        v4i* Bn = &Bs[buf ^ 1][0];
        const v4i* gnext = Bin + (size_t)(nb0 + it + 1) * 2048;

        v16i acc0, acc1;
#pragma unroll
        for (int q = 0; q < 16; ++q) { acc0[q] = tq[q]; acc1[q] = 0; }

        v4i c0 = Bb[0 * 64 + lane], c1 = Bb[1 * 64 + lane];
        v4i c2 = Bb[16 * 64 + lane], c3 = Bb[17 * 64 + lane];

#pragma unroll
        for (int p = 0; p < 8; ++p) {
            v4i n0, n1, n2, n3;
            if (p < 7) {                       // batch-issue next phase's 4 reads
                n0 = Bb[(2 * p + 2) * 64 + lane];
                n1 = Bb[(2 * p + 3) * 64 + lane];
                n2 = Bb[(18 + 2 * p) * 64 + lane];
                n3 = Bb[(19 + 2 * p) * 64 + lane];
            }
            if (p < 4 && it < 7) {             // spread next-tile staging
                int j = 2 * p;
                gload16(gnext + j * 256 + wv * 64 + lane,       Bn + j * 256 + wv * 64);
                gload16(gnext + (j + 1) * 256 + wv * 64 + lane, Bn + (j + 1) * 256 + wv * 64);
            }
            __builtin_amdgcn_s_setprio(1);
            acc0 = __builtin_amdgcn_mfma_i32_32x32x32_i8(a[2 * p],      c0, acc0, 0, 0, 0);
            acc1 = __builtin_amdgcn_mfma_i32_32x32x32_i8(a[16 + 2 * p], c2, acc1, 0, 0, 0);
            acc0 = __builtin_amdgcn_mfma_i32_32x32x32_i8(a[2 * p + 1],  c1, acc0, 0, 0, 0);
            acc1 = __builtin_amdgcn_mfma_i32_32x32x32_i8(a[17 + 2 * p], c3, acc1, 0, 0, 0);
            __builtin_amdgcn_s_setprio(0);
            c0 = n0; c1 = n1; c2 = n2; c3 = n3;
        }

        // h = acc0+acc1 already includes -T2; byte = sign(h): +1 -> 0x01, -1 -> 0xFF
        uint32 wds0 = 0, wds1 = 0, wds2 = 0, wds3 = 0;
#pragma unroll
        for (int bq = 0; bq < 4; ++bq) {
            { int h = acc0[bq]      + acc1[bq];      wds0 |= (((uint32)((h >> 31) | 1)) & 0xFFu) << (8 * bq); }
            { int h = acc0[4 + bq]  + acc1[4 + bq];  wds1 |= (((uint32)((h >> 31) | 1)) & 0xFFu) << (8 * bq); }
            { int h = acc0[8 + bq]  + acc1[8 + bq];  wds2 |= (((uint32)((h >> 31) | 1)) & 0xFFu) << (8 * bq); }
            { int h = acc0[12 + bq] + acc1[12 + bq]; wds3 |= (((uint32)((h >> 31) | 1)) & 0xFFu) << (8 * bq); }
        }
        v4i ov; ov[0] = (int)wds0; ov[1] = (int)wds1; ov[2] = (int)wds2; ov[3] = (int)wds3;
        Bout[((size_t)(nb0 + it) * 32 + mt) * 64 + lane] = ov;

        if (it < 7) {
            // stage loads (8/wave) must land; the output store may float.
            asm volatile("s_waitcnt vmcnt(1)" ::: "memory");
            __builtin_amdgcn_s_barrier();
            buf ^= 1;
        }
    }
}

// ---------------------------------------------------------------------------
// Fused persistent kernel: prep -> L1 -> L2 -> L3 -> final with manual grid
// barriers. 512 blocks x 256 thr = exactly 2 blocks/CU co-resident
// (LDS 66 KB, launch_bounds(256,2)). One dispatch => rocprof attribution.
__global__ void __launch_bounds__(256, 2) fused_kernel(KArgs P)
{
    __shared__ v4i Bs[2][2048];                // 64 KB
    __shared__ int Tsh[128];

    // ---------------- prep ----------------
    {
        unsigned char (*T)[1040] = (unsigned char (*)[1040])(&Bs[0][0]);
        for (int b = blockIdx.x; b < 610; b += GRID)
            prep_unit(b, P, T);
    }
    grid_barrier(P.bar);

    // ---------------- layers ----------------
    layer_gemm((const v4i*)P.wa1, (const v4i*)P.actA, P.TH,        (v4i*)P.actB, Bs, Tsh);
    grid_barrier(P.bar);
    layer_gemm((const v4i*)P.wa2, (const v4i*)P.actB, P.TH + 1024, (v4i*)P.actA, Bs, Tsh);
    grid_barrier(P.bar);
    layer_gemm((const v4i*)P.wa3, (const v4i*)P.actA, P.TH + 2048, (v4i*)P.actB, Bs, Tsh);
    grid_barrier(P.bar);

    // ---------------- final 1024 -> 10 + TensorNorm ----------------
    {
        const int lane = threadIdx.x & 63;
        const int wv   = threadIdx.x >> 6;
        if (wv == 0) {
            int nb = blockIdx.x;               // 512 nb tiles, one per block
            const v4i* Bf  = (const v4i*)P.actB + (size_t)nb * 2048;
            const v4i* Af4 = (const v4i*)P.wa4;
            v16i acc;
#pragma unroll
            for (int z = 0; z < 16; ++z) acc[z] = 0;
#pragma unroll
            for (int kk = 0; kk < 32; ++kk) {
                v4i av = Af4[kk * 64 + lane];
                v4i bv = Bf[kk * 64 + lane];
                acc = __builtin_amdgcn_mfma_i32_32x32x32_i8(av, bv, acc, 0, 0, 0);
            }
            double sc  = (double)P.tw[0] / sqrt((double)P.tv[0] + 1e-4);
            double off = (double)P.tb[0] - (double)P.tm[0] * sc;
            int colg = nb * 32 + (lane & 31);
            int hi   = lane >> 5;
#pragma unroll
            for (int q = 0; q < 8; ++q) {
                int rr = (q & 3) + 8 * (q >> 2) + 4 * hi;
                if (rr < 10)
                    P.out[(size_t)colg * 10 + rr] = (float)((double)acc[q] * sc + off);
            }
        }
    }
}

// ---------------------------------------------------------------------------
extern "C" void kernel_launch(void* const* d_in, const int* in_sizes, int n_in,
                              void* d_out, int out_size, void* d_ws, size_t ws_size,
                              hipStream_t stream) {
    char* ws = (char*)d_ws;
    KArgs P;
    P.x  = (const float*)d_in[0];
    P.W1 = (const float*)d_in[1];
    P.W2 = (const float*)d_in[2];
    P.W3 = (const float*)d_in[3];
    P.W4 = (const float*)d_in[4];
    P.g1 = (const float*)d_in[5];  P.b1 = (const float*)d_in[6];
    P.m1 = (const float*)d_in[7];  P.v1 = (const float*)d_in[8];
    P.g2 = (const float*)d_in[9];  P.b2 = (const float*)d_in[10];
    P.m2 = (const float*)d_in[11]; P.v2 = (const float*)d_in[12];
    P.g3 = (const float*)d_in[13]; P.b3 = (const float*)d_in[14];
    P.m3 = (const float*)d_in[15]; P.v3 = (const float*)d_in[16];
    P.tw = (const float*)d_in[17]; P.tb = (const float*)d_in[18];
    P.tm = (const float*)d_in[19]; P.tv = (const float*)d_in[20];
    P.actA = ws + OFF_ACTA;
    P.actB = ws + OFF_ACTB;
    P.wa1  = ws + OFF_WA1;
    P.wa2  = ws + OFF_WA2;
    P.wa3  = ws + OFF_WA3;
    P.wa4  = ws + OFF_WA4;
    P.TH   = (int*)(ws + OFF_TH);
    P.bar  = (int*)(ws + OFF_BAR);
    P.out  = (float*)d_out;

    hipMemsetAsync(ws + OFF_BAR, 0, 64, stream);   // zero barrier counters
    fused_kernel<<<dim3(GRID), dim3(256), 0, stream>>>(P);
}

// Round 7
// 198.923 us; speedup vs baseline: 2.9182x; 2.9182x over previous
//
#include <hip/hip_runtime.h>
#include <stdint.h>

typedef int  v4i  __attribute__((ext_vector_type(4)));
typedef int  v16i __attribute__((ext_vector_type(16)));
typedef unsigned int uint32;

#define BATCH 16384
#define FEAT  1024

// ---- workspace layout (bytes) ----
// Activations in MFMA B-fragment layout: frag16B index = (nb*32 + kk)*64 + lane
//   value(byte j) = act[row = kk*32 + (j&3) + 8*(j>>2) + 4*(lane>>5)][col = nb*32 + (lane&31)]
// Weights in matching A-fragment layout (same sigma permutation of K).
// W rows with BN scale < 0 are sign-folded (negated) at prep; threshold is a
// single int T2 per row, uniform test h >= T2.
#define OFF_ACTA 0u            // 16 MB  (Xp / H2)
#define OFF_ACTB 16777216u     // 16 MB  (H1 / H3)
#define OFF_WA1  33554432u     // 1 MB
#define OFF_WA2  34603008u     // 1 MB
#define OFF_WA3  35651584u     // 1 MB
#define OFF_WA4  36700160u     // 32 KB (10 rows + 22 zero-pad rows)
#define OFF_TH   36732928u     // 3*1024 int

// ---------------------------------------------------------------------------
// prep: binarize to +-1 int8 (sign-folded for W1..W3) and emit MFMA fragment
// layouts. Roles: b<512: X (thr 0.5) | 512..607: W1..W3 (fold) | 608: W4 | 609: TH
__global__ void __launch_bounds__(256) prep_kernel(
    const float* __restrict__ x,
    const float* __restrict__ W1, const float* __restrict__ W2,
    const float* __restrict__ W3, const float* __restrict__ W4,
    const float* __restrict__ g1, const float* __restrict__ b1,
    const float* __restrict__ m1, const float* __restrict__ v1,
    const float* __restrict__ g2, const float* __restrict__ b2,
    const float* __restrict__ m2, const float* __restrict__ v2,
    const float* __restrict__ g3, const float* __restrict__ b3,
    const float* __restrict__ m3, const float* __restrict__ v3,
    char* __restrict__ actA, char* __restrict__ wa1, char* __restrict__ wa2,
    char* __restrict__ wa3, char* __restrict__ wa4, int* __restrict__ TH)
{
    int b = blockIdx.x;
    if (b == 609) {                       // thresholds, sign-folded to single int
        for (int gid = threadIdx.x; gid < 3072; gid += 256) {
            int l = gid >> 10, j = gid & 1023;
            const float *g, *bb, *m, *v;
            if (l == 0)      { g = g1; bb = b1; m = m1; v = v1; }
            else if (l == 1) { g = g2; bb = b2; m = m2; v = v2; }
            else             { g = g3; bb = b3; m = m3; v = v3; }
            double gd = (double)g[j], bd = (double)bb[j], md = (double)m[j], vd = (double)v[j];
            double s = gd / sqrt(vd + 1e-5);
            int t2;
            if (s > 0.0)      t2 = (int)ceil(md - bd / s);           // bit = h >= t2
            else if (s < 0.0) t2 = -(int)floor(md - bd / s);         // folded
            else              t2 = (bd >= 0.0) ? -2000000 : 2000000; // always / never
            TH[gid] = t2;
        }
        return;
    }

    const float* src; char* dst; float thr; int nrows; int dblk;
    const float* gp = nullptr;
    if (b < 512)      { src = x  + (size_t)b * 32768;            dst = actA; dblk = b;      thr = 0.5f; nrows = 32; }
    else if (b < 544) { int mb = b - 512; src = W1 + (size_t)mb * 32768; dst = wa1; dblk = mb; thr = 0.0f; nrows = 32; gp = g1; }
    else if (b < 576) { int mb = b - 544; src = W2 + (size_t)mb * 32768; dst = wa2; dblk = mb; thr = 0.0f; nrows = 32; gp = g2; }
    else if (b < 608) { int mb = b - 576; src = W3 + (size_t)mb * 32768; dst = wa3; dblk = mb; thr = 0.0f; nrows = 32; gp = g3; }
    else              { src = W4; dst = wa4; dblk = 0; thr = 0.0f; nrows = 10; }

    __shared__ unsigned char T[32][1040];
#pragma unroll
    for (int u = 0; u < 8; ++u) {
        int unit = threadIdx.x + u * 256;      // 0..2047
        int row  = unit >> 6;                  // 0..31
        int c16  = (unit & 63) << 4;           // col base (16 floats)
        uint32 wb0 = 0, wb1 = 0, wb2 = 0, wb3 = 0;
        if (row < nrows) {
            bool flipb = gp && (gp[dblk * 32 + row] < 0.0f);
            const float* p = src + (size_t)row * 1024 + c16;
            float4 f0 = *(const float4*)(p + 0);
            float4 f1 = *(const float4*)(p + 4);
            float4 f2 = *(const float4*)(p + 8);
            float4 f3 = *(const float4*)(p + 12);
#define BY(f) ((((f) >= thr) != flipb) ? 0x01u : 0xFFu)
            wb0 = BY(f0.x) | (BY(f0.y)<<8) | (BY(f0.z)<<16) | (BY(f0.w)<<24);
            wb1 = BY(f1.x) | (BY(f1.y)<<8) | (BY(f1.z)<<16) | (BY(f1.w)<<24);
            wb2 = BY(f2.x) | (BY(f2.y)<<8) | (BY(f2.z)<<16) | (BY(f2.w)<<24);
            wb3 = BY(f3.x) | (BY(f3.y)<<8) | (BY(f3.z)<<16) | (BY(f3.w)<<24);
#undef BY
        }
        *(uint4*)&T[row][c16] = make_uint4(wb0, wb1, wb2, wb3);
    }
    __syncthreads();

    int lane = threadIdx.x & 63;
    int wv   = threadIdx.x >> 6;
    int row  = lane & 31;
    int hb   = (lane >> 5) * 4;                 // +4h byte offset of sigma
#pragma unroll
    for (int u = 0; u < 8; ++u) {
        int kk = wv * 8 + u;
        const unsigned char* tr = &T[row][kk * 32 + hb];
        uint32 w0 = *(const uint32*)(tr + 0);
        uint32 w1 = *(const uint32*)(tr + 8);
        uint32 w2 = *(const uint32*)(tr + 16);
        uint32 w3 = *(const uint32*)(tr + 24);
        *(uint4*)(dst + (((size_t)dblk * 32 + kk) * 64 + lane) * 16) = make_uint4(w0, w1, w2, w3);
    }
}

// ---------------------------------------------------------------------------
__device__ __forceinline__ void gload16(const v4i* gsrc, v4i* ldst) {
    __builtin_amdgcn_global_load_lds(
        (const __attribute__((address_space(1))) void*)gsrc,
        (__attribute__((address_space(3))) void*)ldst, 16, 0, 0);
}

// ---------------------------------------------------------------------------
// Binary GEMM layer on matrix cores: H^T = sign( W_folded @ Hprev^T - T2 ).
// R7: exact R4-verified structure; single delta = next-tile gload_lds issued
// BEFORE the phase's ds_read batch (independent ops, earlier vmem issue).
__global__ void __launch_bounds__(256, 2) gemm_i8_kernel(
    const v4i* __restrict__ Af, const v4i* __restrict__ Bin,
    const int* __restrict__ th, v4i* __restrict__ Bout)
{
    __shared__ v4i Bs[2][2048];                // 2 x 32 KB
    __shared__ int Tsh[128];
    const int tid  = threadIdx.x;
    const int lane = tid & 63;
    const int wv   = tid >> 6;
    int bid = blockIdx.x;
    int xcd = bid & 7;
    int i   = bid >> 3;
    int s   = xcd + ((i >> 3) << 3);           // n-split 0..63, XCD-grouped
    int m   = i & 7;                           // m-block (128 rows)
    int mt  = m * 4 + wv;                      // 32-row W tile 0..31
    int nb0 = s * 8;

    // stage tile 0 (8 gload_lds per wave)
#pragma unroll
    for (int j = 0; j < 8; ++j)
        gload16(Bin + (size_t)nb0 * 2048 + j * 256 + wv * 64 + lane,
                &Bs[0][j * 256 + wv * 64]);
    if (tid < 128) Tsh[tid] = th[m * 128 + tid];

    // A-fragments, full K (32 x 16B = 128 VGPR)
    v4i a[32];
    {
        const v4i* Ap = Af + (size_t)mt * 2048;
#pragma unroll
        for (int kk = 0; kk < 32; ++kk) a[kk] = Ap[kk * 64 + lane];
    }
    asm volatile("s_waitcnt vmcnt(0) lgkmcnt(0)" ::: "memory");
    __builtin_amdgcn_s_barrier();

    // hoist thresholds (negated) into 16 regs, C-layout order
    const int hi4 = (lane >> 5) * 4;
    int tq[16];
#pragma unroll
    for (int q = 0; q < 16; ++q) tq[q] = -Tsh[wv * 32 + (q & 3) + 8 * (q >> 2) + hi4];

    int buf = 0;
#pragma unroll 1
    for (int it = 0; it < 8; ++it) {
        const v4i* Bb = &Bs[buf][0];
        v4i* Bn = &Bs[buf ^ 1][0];
        const v4i* gnext = Bin + (size_t)(nb0 + it + 1) * 2048;

        v16i acc0, acc1;
#pragma unroll
        for (int q = 0; q < 16; ++q) { acc0[q] = tq[q]; acc1[q] = 0; }

        v4i c0 = Bb[0 * 64 + lane], c1 = Bb[1 * 64 + lane];
        v4i c2 = Bb[16 * 64 + lane], c3 = Bb[17 * 64 + lane];

#pragma unroll
        for (int p = 0; p < 8; ++p) {
            if (p < 4 && it < 7) {             // issue next-tile staging FIRST
                int j = 2 * p;
                gload16(gnext + j * 256 + wv * 64 + lane,       Bn + j * 256 + wv * 64);
                gload16(gnext + (j + 1) * 256 + wv * 64 + lane, Bn + (j + 1) * 256 + wv * 64);
            }
            v4i n0, n1, n2, n3;
            if (p < 7) {                       // batch-issue next phase's 4 reads
                n0 = Bb[(2 * p + 2) * 64 + lane];
                n1 = Bb[(2 * p + 3) * 64 + lane];
                n2 = Bb[(18 + 2 * p) * 64 + lane];
                n3 = Bb[(19 + 2 * p) * 64 + lane];
            }
            __builtin_amdgcn_s_setprio(1);
            acc0 = __builtin_amdgcn_mfma_i32_32x32x32_i8(a[2 * p],      c0, acc0, 0, 0, 0);
            acc1 = __builtin_amdgcn_mfma_i32_32x32x32_i8(a[16 + 2 * p], c2, acc1, 0, 0, 0);
            acc0 = __builtin_amdgcn_mfma_i32_32x32x32_i8(a[2 * p + 1],  c1, acc0, 0, 0, 0);
            acc1 = __builtin_amdgcn_mfma_i32_32x32x32_i8(a[17 + 2 * p], c3, acc1, 0, 0, 0);
            __builtin_amdgcn_s_setprio(0);
            c0 = n0; c1 = n1; c2 = n2; c3 = n3;
        }

        // h = acc0+acc1 already includes -T2; byte = sign(h): +1 -> 0x01, -1 -> 0xFF
        uint32 wds0 = 0, wds1 = 0, wds2 = 0, wds3 = 0;
#pragma unroll
        for (int bq = 0; bq < 4; ++bq) {
            { int h = acc0[bq]      + acc1[bq];      wds0 |= (((uint32)((h >> 31) | 1)) & 0xFFu) << (8 * bq); }
            { int h = acc0[4 + bq]  + acc1[4 + bq];  wds1 |= (((uint32)((h >> 31) | 1)) & 0xFFu) << (8 * bq); }
            { int h = acc0[8 + bq]  + acc1[8 + bq];  wds2 |= (((uint32)((h >> 31) | 1)) & 0xFFu) << (8 * bq); }
            { int h = acc0[12 + bq] + acc1[12 + bq]; wds3 |= (((uint32)((h >> 31) | 1)) & 0xFFu) << (8 * bq); }
        }
        v4i ov; ov[0] = (int)wds0; ov[1] = (int)wds1; ov[2] = (int)wds2; ov[3] = (int)wds3;
        Bout[((size_t)(nb0 + it) * 32 + mt) * 64 + lane] = ov;

        if (it < 7) {
            // stage loads (8/wave) must land; the output store may float.
            asm volatile("s_waitcnt vmcnt(1)" ::: "memory");
            __builtin_amdgcn_s_barrier();
            buf ^= 1;
        }
    }
}

// ---------------------------------------------------------------------------
// Final 1024 -> 10 via MFMA (W4 zero-padded to 32 rows) + TensorNorm.
__global__ void __launch_bounds__(128) final_kernel(
    const v4i* __restrict__ Af4, const v4i* __restrict__ B3,
    const float* __restrict__ tw, const float* __restrict__ tb,
    const float* __restrict__ tm, const float* __restrict__ tv,
    float* __restrict__ out)
{
    int lane = threadIdx.x & 63;
    int nb   = blockIdx.x * 2 + (threadIdx.x >> 6);
    const v4i* Bf = B3 + (size_t)nb * 2048;
    v16i acc;
#pragma unroll
    for (int z = 0; z < 16; ++z) acc[z] = 0;
#pragma unroll
    for (int kk = 0; kk < 32; ++kk) {
        v4i av = Af4[kk * 64 + lane];
        v4i bv = Bf[kk * 64 + lane];
        acc = __builtin_amdgcn_mfma_i32_32x32x32_i8(av, bv, acc, 0, 0, 0);
    }
    double sc  = (double)tw[0] / sqrt((double)tv[0] + 1e-4);
    double off = (double)tb[0] - (double)tm[0] * sc;
    int colg = nb * 32 + (lane & 31);
    int hi   = lane >> 5;
#pragma unroll
    for (int q = 0; q < 8; ++q) {
        int rr = (q & 3) + 8 * (q >> 2) + 4 * hi;
        if (rr < 10)
            out[(size_t)colg * 10 + rr] = (float)((double)acc[q] * sc + off);
    }
}

// ---------------------------------------------------------------------------
extern "C" void kernel_launch(void* const* d_in, const int* in_sizes, int n_in,
                              void* d_out, int out_size, void* d_ws, size_t ws_size,
                              hipStream_t stream) {
    const float* x  = (const float*)d_in[0];
    const float* W1 = (const float*)d_in[1];
    const float* W2 = (const float*)d_in[2];
    const float* W3 = (const float*)d_in[3];
    const float* W4 = (const float*)d_in[4];
    const float* g1 = (const float*)d_in[5];
    const float* b1 = (const float*)d_in[6];
    const float* m1 = (const float*)d_in[7];
    const float* v1 = (const float*)d_in[8];
    const float* g2 = (const float*)d_in[9];
    const float* b2 = (const float*)d_in[10];
    const float* m2 = (const float*)d_in[11];
    const float* v2 = (const float*)d_in[12];
    const float* g3 = (const float*)d_in[13];
    const float* b3 = (const float*)d_in[14];
    const float* m3 = (const float*)d_in[15];
    const float* v3 = (const float*)d_in[16];
    const float* tw = (const float*)d_in[17];
    const float* tb = (const float*)d_in[18];
    const float* tm = (const float*)d_in[19];
    const float* tv = (const float*)d_in[20];

    char* ws = (char*)d_ws;
    char* actA = ws + OFF_ACTA;
    char* actB = ws + OFF_ACTB;
    char* wa1  = ws + OFF_WA1;
    char* wa2  = ws + OFF_WA2;
    char* wa3  = ws + OFF_WA3;
    char* wa4  = ws + OFF_WA4;
    int*  TH   = (int*)(ws + OFF_TH);

    prep_kernel<<<610, 256, 0, stream>>>(x, W1, W2, W3, W4,
                                         g1, b1, m1, v1, g2, b2, m2, v2,
                                         g3, b3, m3, v3,
                                         actA, wa1, wa2, wa3, wa4, TH);

    gemm_i8_kernel<<<512, 256, 0, stream>>>((const v4i*)wa1, (const v4i*)actA, TH,        (v4i*)actB);
    gemm_i8_kernel<<<512, 256, 0, stream>>>((const v4i*)wa2, (const v4i*)actB, TH + 1024, (v4i*)actA);
    gemm_i8_kernel<<<512, 256, 0, stream>>>((const v4i*)wa3, (const v4i*)actA, TH + 2048, (v4i*)actB);

    final_kernel<<<256, 128, 0, stream>>>((const v4i*)wa4, (const v4i*)actB,
                                          tw, tb, tm, tv, (float*)d_out);
}

// Round 8
// 197.899 us; speedup vs baseline: 2.9333x; 1.0052x over previous
//
#include <hip/hip_runtime.h>
#include <stdint.h>

typedef int  v4i  __attribute__((ext_vector_type(4)));
typedef int  v16i __attribute__((ext_vector_type(16)));
typedef unsigned int uint32;

#define BATCH 16384
#define FEAT  1024

// ---- workspace layout (bytes) ----
// Activations/weights in MFMA fragment layout: frag16B idx = (tile*32+kk)*64+lane
//   byte j of lane = val[row = kk*32 + (j&3)+8*(j>>2)+4*(lane>>5)][col = tile*32 + (lane&31)]
// W rows with BN scale < 0 sign-folded at prep. Thresholds stored in SIGMA
// order: TH[l*1024 + mt*32 + hi*16 + q] = t2(row = mt*32+(q&3)+8*(q>>2)+4*hi).
#define OFF_ACTA 0u            // 16 MB  (packed X)
#define OFF_ACTB 16777216u     // (unused in R8 — kept for layout stability)
#define OFF_WA1  33554432u     // 1 MB
#define OFF_WA2  34603008u     // 1 MB
#define OFF_WA3  35651584u     // 1 MB
#define OFF_WA4  36700160u     // 32 KB (10 rows + 22 zero-pad rows)
#define OFF_TH   36732928u     // 3*1024 int (sigma order)

// ---------------------------------------------------------------------------
// prep (R4-verified; only change: TH written in sigma order).
__global__ void __launch_bounds__(256) prep_kernel(
    const float* __restrict__ x,
    const float* __restrict__ W1, const float* __restrict__ W2,
    const float* __restrict__ W3, const float* __restrict__ W4,
    const float* __restrict__ g1, const float* __restrict__ b1,
    const float* __restrict__ m1, const float* __restrict__ v1,
    const float* __restrict__ g2, const float* __restrict__ b2,
    const float* __restrict__ m2, const float* __restrict__ v2,
    const float* __restrict__ g3, const float* __restrict__ b3,
    const float* __restrict__ m3, const float* __restrict__ v3,
    char* __restrict__ actA, char* __restrict__ wa1, char* __restrict__ wa2,
    char* __restrict__ wa3, char* __restrict__ wa4, int* __restrict__ TH)
{
    int b = blockIdx.x;
    if (b == 609) {                       // thresholds, sign-folded, sigma order
        for (int gid = threadIdx.x; gid < 3072; gid += 256) {
            int l = gid >> 10, j = gid & 1023;
            const float *g, *bb, *m, *v;
            if (l == 0)      { g = g1; bb = b1; m = m1; v = v1; }
            else if (l == 1) { g = g2; bb = b2; m = m2; v = v2; }
            else             { g = g3; bb = b3; m = m3; v = v3; }
            double gd = (double)g[j], bd = (double)bb[j], md = (double)m[j], vd = (double)v[j];
            double s = gd / sqrt(vd + 1e-5);
            int t2;
            if (s > 0.0)      t2 = (int)ceil(md - bd / s);           // bit = h >= t2
            else if (s < 0.0) t2 = -(int)floor(md - bd / s);         // folded
            else              t2 = (bd >= 0.0) ? -2000000 : 2000000; // always / never
            // sigma order: row j -> mt=j>>5, hi=(j>>2)&1, q=(j&3)+4*((j&31)>>3)
            int sidx = (j >> 5) * 32 + ((j >> 2) & 1) * 16 + (j & 3) + 4 * ((j & 31) >> 3);
            TH[l * 1024 + sidx] = t2;
        }
        return;
    }

    const float* src; char* dst; float thr; int nrows; int dblk;
    const float* gp = nullptr;
    if (b < 512)      { src = x  + (size_t)b * 32768;            dst = actA; dblk = b;      thr = 0.5f; nrows = 32; }
    else if (b < 544) { int mb = b - 512; src = W1 + (size_t)mb * 32768; dst = wa1; dblk = mb; thr = 0.0f; nrows = 32; gp = g1; }
    else if (b < 576) { int mb = b - 544; src = W2 + (size_t)mb * 32768; dst = wa2; dblk = mb; thr = 0.0f; nrows = 32; gp = g2; }
    else if (b < 608) { int mb = b - 576; src = W3 + (size_t)mb * 32768; dst = wa3; dblk = mb; thr = 0.0f; nrows = 32; gp = g3; }
    else              { src = W4; dst = wa4; dblk = 0; thr = 0.0f; nrows = 10; }

    __shared__ unsigned char T[32][1040];
#pragma unroll
    for (int u = 0; u < 8; ++u) {
        int unit = threadIdx.x + u * 256;      // 0..2047
        int row  = unit >> 6;                  // 0..31
        int c16  = (unit & 63) << 4;           // col base (16 floats)
        uint32 wb0 = 0, wb1 = 0, wb2 = 0, wb3 = 0;
        if (row < nrows) {
            bool flipb = gp && (gp[dblk * 32 + row] < 0.0f);
            const float* p = src + (size_t)row * 1024 + c16;
            float4 f0 = *(const float4*)(p + 0);
            float4 f1 = *(const float4*)(p + 4);
            float4 f2 = *(const float4*)(p + 8);
            float4 f3 = *(const float4*)(p + 12);
#define BY(f) ((((f) >= thr) != flipb) ? 0x01u : 0xFFu)
            wb0 = BY(f0.x) | (BY(f0.y)<<8) | (BY(f0.z)<<16) | (BY(f0.w)<<24);
            wb1 = BY(f1.x) | (BY(f1.y)<<8) | (BY(f1.z)<<16) | (BY(f1.w)<<24);
            wb2 = BY(f2.x) | (BY(f2.y)<<8) | (BY(f2.z)<<16) | (BY(f2.w)<<24);
            wb3 = BY(f3.x) | (BY(f3.y)<<8) | (BY(f3.z)<<16) | (BY(f3.w)<<24);
#undef BY
        }
        *(uint4*)&T[row][c16] = make_uint4(wb0, wb1, wb2, wb3);
    }
    __syncthreads();

    int lane = threadIdx.x & 63;
    int wv   = threadIdx.x >> 6;
    int row  = lane & 31;
    int hb   = (lane >> 5) * 4;                 // +4h byte offset of sigma
#pragma unroll
    for (int u = 0; u < 8; ++u) {
        int kk = wv * 8 + u;
        const unsigned char* tr = &T[row][kk * 32 + hb];
        uint32 w0 = *(const uint32*)(tr + 0);
        uint32 w1 = *(const uint32*)(tr + 8);
        uint32 w2 = *(const uint32*)(tr + 16);
        uint32 w3 = *(const uint32*)(tr + 24);
        *(uint4*)(dst + (((size_t)dblk * 32 + kk) * 64 + lane) * 16) = make_uint4(w0, w1, w2, w3);
    }
}

// ---------------------------------------------------------------------------
__device__ __forceinline__ void gload16(const v4i* gsrc, v4i* ldst) {
    __builtin_amdgcn_global_load_lds(
        (const __attribute__((address_space(1))) void*)gsrc,
        (__attribute__((address_space(3))) void*)ldst, 16, 0, 0);
}

#define MFMA(a, b, c) __builtin_amdgcn_mfma_i32_32x32x32_i8((a), (b), (c), 0, 0, 0)

// ---------------------------------------------------------------------------
// R8: whole-network batch-fused kernel. Block owns 64 batch columns; all 3
// hidden layers + final run with activations resident in LDS (H = 2 nb tiles
// x 32 kk frags = 64 KB). W streamed from global (L2-resident: 3 MB/XCD).
// No grid-wide sync needed (batch columns are independent) => correct at any
// occupancy. 16 waves/block, VGPR must stay <= 128 (launch_bounds(1024,4)).
__global__ void __launch_bounds__(1024, 4) net_kernel(
    const v4i* __restrict__ Xp,  const v4i* __restrict__ Wp1,
    const v4i* __restrict__ Wp2, const v4i* __restrict__ Wp3,
    const v4i* __restrict__ Wp4, const int* __restrict__ TH,
    const float* __restrict__ tw, const float* __restrict__ tb,
    const float* __restrict__ tm, const float* __restrict__ tv,
    float* __restrict__ out)
{
    __shared__ v4i Hs[4096];               // 64 KB: frag f = nb*32+kk at f*64+lane
    const int tid  = threadIdx.x;
    const int lane = tid & 63;
    const int wv   = tid >> 6;             // 0..15
    const int hi   = lane >> 5;
    const int blk  = blockIdx.x;           // 0..255, owns cols blk*64..+63

    // ---- load packed X for this block's 2 nb tiles (64 KB, linear) ----
    {
        const v4i* src = Xp + (size_t)blk * 4096;
#pragma unroll
        for (int j = 0; j < 4; ++j)
            gload16(src + j * 1024 + wv * 64 + lane, &Hs[j * 1024 + wv * 64]);
    }
    asm volatile("s_waitcnt vmcnt(0)" ::: "memory");
    __syncthreads();

    const int mt0 = wv * 2, mt1 = wv * 2 + 1;
    const v4i* Ws[3] = { Wp1, Wp2, Wp3 };

#pragma unroll 1
    for (int l = 0; l < 3; ++l) {
        const v4i* W = Ws[l];
        const int* thl = TH + l * 1024;

        // acc pre-initialized with -T2 (sigma-ordered threshold load)
        v16i acc00, acc01, acc10, acc11;
        {
            const int4* t0 = (const int4*)(thl + mt0 * 32 + hi * 16);
            const int4* t1 = (const int4*)(thl + mt1 * 32 + hi * 16);
#pragma unroll
            for (int g = 0; g < 4; ++g) {
                int4 ta = t0[g], tc = t1[g];
                acc00[4*g+0] = -ta.x; acc00[4*g+1] = -ta.y;
                acc00[4*g+2] = -ta.z; acc00[4*g+3] = -ta.w;
                acc10[4*g+0] = -tc.x; acc10[4*g+1] = -tc.y;
                acc10[4*g+2] = -tc.z; acc10[4*g+3] = -tc.w;
            }
#pragma unroll
            for (int q = 0; q < 16; ++q) { acc01[q] = acc00[q]; acc11[q] = acc10[q]; }
        }

        const v4i* A0 = W + (size_t)mt0 * 2048 + lane;
        const v4i* A1 = W + (size_t)mt1 * 2048 + lane;
#pragma unroll 2
        for (int kk = 0; kk < 32; ++kk) {
            v4i b0 = Hs[kk * 64 + lane];
            v4i b1 = Hs[(32 + kk) * 64 + lane];
            v4i a0 = A0[kk * 64];
            v4i a1 = A1[kk * 64];
            acc00 = MFMA(a0, b0, acc00);
            acc01 = MFMA(a0, b1, acc01);
            acc10 = MFMA(a1, b0, acc10);
            acc11 = MFMA(a1, b1, acc11);
        }

        // threshold -> bytes (h includes -T2; byte = sign: +1->0x01, -1->0xFF)
        uint32 w00[4], w01[4], w10[4], w11[4];
#pragma unroll
        for (int g = 0; g < 4; ++g) {
            uint32 d00 = 0, d01 = 0, d10 = 0, d11 = 0;
#pragma unroll
            for (int bq = 0; bq < 4; ++bq) {
                int q = 4 * g + bq;
                d00 |= (((uint32)((acc00[q] >> 31) | 1)) & 0xFFu) << (8 * bq);
                d01 |= (((uint32)((acc01[q] >> 31) | 1)) & 0xFFu) << (8 * bq);
                d10 |= (((uint32)((acc10[q] >> 31) | 1)) & 0xFFu) << (8 * bq);
                d11 |= (((uint32)((acc11[q] >> 31) | 1)) & 0xFFu) << (8 * bq);
            }
            w00[g] = d00; w01[g] = d01; w10[g] = d10; w11[g] = d11;
        }

        __syncthreads();                   // all waves done READING Hs
        {
            v4i o;
            o[0] = (int)w00[0]; o[1] = (int)w00[1]; o[2] = (int)w00[2]; o[3] = (int)w00[3];
            Hs[(0 * 32 + mt0) * 64 + lane] = o;      // (mt0, nb0) -> frag kk=mt0
            o[0] = (int)w01[0]; o[1] = (int)w01[1]; o[2] = (int)w01[2]; o[3] = (int)w01[3];
            Hs[(32 + mt0) * 64 + lane] = o;          // (mt0, nb1)
            o[0] = (int)w10[0]; o[1] = (int)w10[1]; o[2] = (int)w10[2]; o[3] = (int)w10[3];
            Hs[(0 * 32 + mt1) * 64 + lane] = o;      // (mt1, nb0)
            o[0] = (int)w11[0]; o[1] = (int)w11[1]; o[2] = (int)w11[2]; o[3] = (int)w11[3];
            Hs[(32 + mt1) * 64 + lane] = o;          // (mt1, nb1)
        }
        __syncthreads();                   // new layer visible to all waves
    }

    // ---- final 1024 -> 10 (W4 zero-padded to 32 rows) + TensorNorm ----
    if (wv < 2) {
        const int nb = wv;
        v16i acc;
#pragma unroll
        for (int z = 0; z < 16; ++z) acc[z] = 0;
#pragma unroll
        for (int kk = 0; kk < 32; ++kk) {
            v4i av = Wp4[kk * 64 + lane];
            v4i bv = Hs[(nb * 32 + kk) * 64 + lane];
            acc = MFMA(av, bv, acc);
        }
        double sc  = (double)tw[0] / sqrt((double)tv[0] + 1e-4);
        double off = (double)tb[0] - (double)tm[0] * sc;
        int colg = blk * 64 + nb * 32 + (lane & 31);
#pragma unroll
        for (int q = 0; q < 8; ++q) {
            int rr = (q & 3) + 8 * (q >> 2) + 4 * hi;
            if (rr < 10)
                out[(size_t)colg * 10 + rr] = (float)((double)acc[q] * sc + off);
        }
    }
}

// ---------------------------------------------------------------------------
extern "C" void kernel_launch(void* const* d_in, const int* in_sizes, int n_in,
                              void* d_out, int out_size, void* d_ws, size_t ws_size,
                              hipStream_t stream) {
    const float* x  = (const float*)d_in[0];
    const float* W1 = (const float*)d_in[1];
    const float* W2 = (const float*)d_in[2];
    const float* W3 = (const float*)d_in[3];
    const float* W4 = (const float*)d_in[4];
    const float* g1 = (const float*)d_in[5];
    const float* b1 = (const float*)d_in[6];
    const float* m1 = (const float*)d_in[7];
    const float* v1 = (const float*)d_in[8];
    const float* g2 = (const float*)d_in[9];
    const float* b2 = (const float*)d_in[10];
    const float* m2 = (const float*)d_in[11];
    const float* v2 = (const float*)d_in[12];
    const float* g3 = (const float*)d_in[13];
    const float* b3 = (const float*)d_in[14];
    const float* m3 = (const float*)d_in[15];
    const float* v3 = (const float*)d_in[16];
    const float* tw = (const float*)d_in[17];
    const float* tb = (const float*)d_in[18];
    const float* tm = (const float*)d_in[19];
    const float* tv = (const float*)d_in[20];

    char* ws = (char*)d_ws;
    char* actA = ws + OFF_ACTA;
    char* wa1  = ws + OFF_WA1;
    char* wa2  = ws + OFF_WA2;
    char* wa3  = ws + OFF_WA3;
    char* wa4  = ws + OFF_WA4;
    int*  TH   = (int*)(ws + OFF_TH);

    prep_kernel<<<610, 256, 0, stream>>>(x, W1, W2, W3, W4,
                                         g1, b1, m1, v1, g2, b2, m2, v2,
                                         g3, b3, m3, v3,
                                         actA, wa1, wa2, wa3, wa4, TH);

    net_kernel<<<256, 1024, 0, stream>>>((const v4i*)actA,
                                         (const v4i*)wa1, (const v4i*)wa2,
                                         (const v4i*)wa3, (const v4i*)wa4,
                                         TH, tw, tb, tm, tv, (float*)d_out);
}